// Round 13
// baseline (47.552 us; speedup 1.0000x reference)
//
#include <hip/hip_runtime.h>

typedef __bf16 v8bf __attribute__((ext_vector_type(8)));
typedef float f32x4 __attribute__((ext_vector_type(4)));

#define C_IN 256
#define HW   64
#define OHW  63
#define NOC  128

// Wf: [kp(4)][khkw(4)][cblk(32)][oc(128)][j(8)] bf16, 1 MiB. Coalesced.
__global__ void wprep(const float* __restrict__ w, __bf16* __restrict__ Wf) {
  int f = blockIdx.x;                 // 512 filters
  int c = threadIdx.x;                // 256 channels
  f32x4 v = *(const f32x4*)(w + (size_t)f * 1024 + c * 4);  // 4 khkw taps
  int oc = f >> 2, kp = f & 3;
#pragma unroll
  for (int khkw = 0; khkw < 4; ++khkw)
    Wf[(((size_t)(kp * 4 + khkw) * 32 + (c >> 3)) * 128 + oc) * 8 + (c & 7)] =
        (__bf16)v[khkw];
}

// 8-wave/256-VGPR package on the R12 structure. Block: n x 4 out rows x
// 128 oc, 512 thr (8 waves = 2 ocg x 4 kp, 2/SIMD, 1 block/CU).
// Per wave: m=4 A-frags (64 oc) x f=4 px-frags -> B ds_reads halve vs R12.
// 2-deep x prefetch (xrA/xrB banks): WRITEQ(q+1) consumes data issued a
// full iteration earlier; vmcnt never drains to 0 in the loop.
// LDS loop tile: [dy(5)][wpair(33)][par(2)][c(32)] bf16 XOR-swizzled, dbuf;
// reused post-loop as [oc(128)][68] f32 for the transposed epilogue.
__global__ __launch_bounds__(512, 2) void robin_main(
    const float* __restrict__ x, const __bf16* __restrict__ Wf,
    const float* __restrict__ bias, float* __restrict__ out) {
  __shared__ __align__(16) char smem[42240];       // 2x21120 loop / 34816 epi
  char* xb0 = smem;
  char* xb1 = smem + 21120;

  const int tid  = threadIdx.x;
  const int lane = tid & 63;
  const int wid  = tid >> 6;         // 0..7
  const int hb   = blockIdx.x;       // 16
  const int n    = blockIdx.y;       // 16
  const int h0   = hb * 4;

  const int ocg  = wid >> 2;         // 0..1 -> 64 oc each
  const int kp   = wid & 3;          // parity class
  const int ph   = kp >> 1, pw = kp & 1;
  const int lcol = lane & 15;        // pixel col (B) / oc row (A)
  const int lg   = lane >> 4;        // k-octet group

  // zero-fill wpair=32 pad rows (wcol 64/65), both buffers
  if (tid < 80) {
    int g  = tid & 7;
    int t2 = tid >> 3;
    int dy = t2 % 5, bi = t2 / 5;
    f32x4 z = {0.f, 0.f, 0.f, 0.f};
    *(f32x4*)((bi ? xb1 : xb0) + (dy * 33 + 32) * 128 + g * 16) = z;
  }

  // chunk-invariant B-frag base offsets (r -> +8448, hh -> +2048; deltas
  // don't touch swizzled bits 4..6)
  int boff[4];
#pragma unroll
  for (int khkw = 0; khkw < 4; ++khkw) {
    int kh = khkw >> 1, kw = khkw & 1;
    int dy0  = ph + kh;
    int wcol = 2 * lcol + pw + kw;
    int wp_  = wcol >> 1;
    boff[khkw] = ((dy0 * 33 + wp_) * 128 + (wcol & 1) * 64 + lg * 16) ^
                 ((wp_ & 7) << 4);
  }

  f32x4 acc[4][4];                   // m(4 oc-frags) x f(4 px-frags) = 64 VGPR
#pragma unroll
  for (int m = 0; m < 4; ++m)
#pragma unroll
    for (int f = 0; f < 4; ++f) acc[m][f] = (f32x4){0.f, 0.f, 0.f, 0.f};

  const float* xbase = x + (size_t)n * C_IN * HW * HW;
  f32x4 xrA[5], xrB[5];              // 2-deep staging banks (5 units/thread)
  v8bf  a_reg[4][4];                 // khkw x m = 64 VGPR

#define A_LOAD(QQ)                                                             \
  {                                                                            \
    _Pragma("unroll") for (int khkw = 0; khkw < 4; ++khkw) {                   \
      const __bf16* wp =                                                       \
          Wf + (((size_t)(kp * 4 + khkw) * 32 + (QQ) * 4 + lg) * 128 +        \
                ocg * 64 + lcol) * 8;                                          \
      _Pragma("unroll") for (int m = 0; m < 4; ++m)                            \
          a_reg[khkw][m] = *(const v8bf*)(wp + m * 128);                       \
    }                                                                          \
  }

  // 2560 float4 units per chunk = 5/thread: v=k*512+tid -> dy=v>>9,
  // c=(v>>4)&31, w4=v&15
#define LOADQ(QQ, XR)                                                          \
  {                                                                            \
    const int cbase = (QQ) * 32;                                               \
    _Pragma("unroll") for (int k = 0; k < 5; ++k) {                            \
      int v = k * 512 + tid;                                                   \
      int w4 = v & 15, c = (v >> 4) & 31, dy = v >> 9;                         \
      int y = h0 + dy;                                                         \
      if (y < HW)                                                              \
        XR[k] = *(const f32x4*)(xbase + ((size_t)(cbase + c) * HW + y) * HW +  \
                                w4 * 4);                                       \
      else                                                                     \
        XR[k] = (f32x4){0.f, 0.f, 0.f, 0.f};                                   \
    }                                                                          \
  }

#define WRITEQ(QQ, XR)                                                         \
  {                                                                            \
    char* xd = ((QQ) & 1) ? xb1 : xb0;                                         \
    _Pragma("unroll") for (int k = 0; k < 5; ++k) {                            \
      int v = k * 512 + tid;                                                   \
      int w4 = v & 15, c = (v >> 4) & 31, dy = v >> 9;                         \
      _Pragma("unroll") for (int j = 0; j < 4; ++j) {                          \
        int wcol = w4 * 4 + j;                                                 \
        int wp_  = wcol >> 1;                                                  \
        int bo = ((dy * 33 + wp_) * 128 + (wcol & 1) * 64 + c * 2) ^           \
                 ((wp_ & 7) << 4);                                             \
        *(__bf16*)(xd + bo) = (__bf16)XR[k][j];                                \
      }                                                                        \
    }                                                                          \
  }

#define COMPUTE(QQ)                                                            \
  {                                                                            \
    const char* xsb = ((QQ) & 1) ? xb1 : xb0;                                  \
    _Pragma("unroll") for (int khkw = 0; khkw < 4; ++khkw) {                   \
      v8bf b[4];                                                               \
      _Pragma("unroll") for (int r = 0; r < 2; ++r)                            \
        _Pragma("unroll") for (int hh = 0; hh < 2; ++hh)                       \
          b[r * 2 + hh] =                                                      \
              *(const v8bf*)(xsb + boff[khkw] + r * 8448 + hh * 2048);         \
      _Pragma("unroll") for (int m = 0; m < 4; ++m)                            \
        _Pragma("unroll") for (int f = 0; f < 4; ++f)                          \
          acc[m][f] = __builtin_amdgcn_mfma_f32_16x16x32_bf16(                 \
              a_reg[khkw][m], b[f], acc[m][f], 0, 0, 0);                       \
    }                                                                          \
  }

  // iter q: A(q) first (vmcnt FIFO), x(q+2)->free bank, compute(q),
  // write(q+1) from the bank filled one full iteration ago, one barrier.
#define ITER(QQ, XRL, XRW)                                                     \
  {                                                                            \
    A_LOAD(QQ);                                                                \
    if ((QQ) < 6) LOADQ((QQ) + 2, XRL);                                        \
    COMPUTE(QQ);                                                               \
    if ((QQ) < 7) {                                                            \
      WRITEQ((QQ) + 1, XRW);                                                   \
      __syncthreads();                                                         \
    }                                                                          \
  }

  // prologue: x(0)->xrA, x(1)->xrB, stage chunk 0
  LOADQ(0, xrA);
  LOADQ(1, xrB);
  WRITEQ(0, xrA);
  __syncthreads();

  ITER(0, xrA, xrB);
  ITER(1, xrB, xrA);
  ITER(2, xrA, xrB);
  ITER(3, xrB, xrA);
  ITER(4, xrA, xrB);
  ITER(5, xrB, xrA);
  ITER(6, xrA, xrB);
  ITER(7, xrB, xrA);

  // ---- epilogue: LDS transpose -> stride-1 coalesced scalar stores ----
  // acc D layout: col=lane&15 (pixel), row=(lane>>4)*4+reg (oc).
  float bv[4][4];
#pragma unroll
  for (int m = 0; m < 4; ++m)
#pragma unroll
    for (int reg = 0; reg < 4; ++reg)
      bv[m][reg] = bias[(ocg * 64 + m * 16 + lg * 4 + reg) * 4 + kp];

  float* eb = (float*)smem;          // [oc(128)][68] f32 = 34816 B
#pragma unroll
  for (int p = 0; p < 4; ++p) {
    const int h = h0 + p;
    __syncthreads();                 // prev pass reads / loop reads done
    if ((ph == (p & 1)) && h < OHW) {
      const int rsel = p >> 1;
#pragma unroll
      for (int m = 0; m < 4; ++m)
#pragma unroll
        for (int hh = 0; hh < 2; ++hh) {
          f32x4 v = acc[m][rsel * 2 + hh];
          int w = 2 * (hh * 16 + lcol) + pw;       // <= 63
#pragma unroll
          for (int reg = 0; reg < 4; ++reg)
            eb[(ocg * 64 + m * 16 + lg * 4 + reg) * 68 + w] =
                v[reg] + bv[m][reg];
        }
    }
    __syncthreads();                 // tile complete
    if (h < OHW) {
      const int lc2 = tid & 15;
#pragma unroll
      for (int s = 0; s < 4; ++s) {
        int oc = (tid >> 4) + (s << 5);            // 32 rows per s
        float* orow = out + ((size_t)(n * NOC + oc) * OHW + h) * OHW;
        const float* erow = eb + oc * 68;
#pragma unroll
        for (int b = 0; b < 4; ++b) {
          int w = lc2 + 16 * b;
          if (w < OHW) orow[w] = erow[w];
        }
      }
    }
  }
#undef A_LOAD
#undef LOADQ
#undef WRITEQ
#undef COMPUTE
#undef ITER
}

extern "C" void kernel_launch(void* const* d_in, const int* in_sizes, int n_in,
                              void* d_out, int out_size, void* d_ws, size_t ws_size,
                              hipStream_t stream) {
  const float* x      = (const float*)d_in[0];
  const float* weight = (const float*)d_in[1];
  const float* bias   = (const float*)d_in[2];
  float* out          = (float*)d_out;
  __bf16* Wf          = (__bf16*)d_ws;   // 1 MiB fragment-ordered weights

  wprep<<<512, 256, 0, stream>>>(weight, Wf);
  robin_main<<<dim3(16, 16), 512, 0, stream>>>(x, Wf, bias, out);
}

// Round 14
// 42.921 us; speedup vs baseline: 1.1079x; 1.1079x over previous
//
#include <hip/hip_runtime.h>

typedef __bf16 v8bf __attribute__((ext_vector_type(8)));
typedef float f32x4 __attribute__((ext_vector_type(4)));
typedef unsigned int u32;

#define C_IN 256
#define HW   64
#define OHW  63
#define NOC  128

// Wf: [kp(4)][khkw(4)][cblk(32)][oc(128)][j(8)] bf16, 1 MiB. Coalesced.
__global__ void wprep(const float* __restrict__ w, __bf16* __restrict__ Wf) {
  int f = blockIdx.x;                 // 512 filters
  int c = threadIdx.x;                // 256 channels
  f32x4 v = *(const f32x4*)(w + (size_t)f * 1024 + c * 4);  // 4 khkw taps
  int oc = f >> 2, kp = f & 3;
#pragma unroll
  for (int khkw = 0; khkw < 4; ++khkw)
    Wf[(((size_t)(kp * 4 + khkw) * 32 + (c >> 3)) * 128 + oc) * 8 + (c & 7)] =
        (__bf16)v[khkw];
}

// R12 structure, staging re-partitioned for b32 LDS writes.
// Block: n x 4 out rows x 128 oc, 1024 thr (16 waves, 4/SIMD).
// wave = ocg(4: 32 oc) x kp(4). Staging: thread owns c-pair (2*wid,2*wid+1)
// at w=lane -> 10 coalesced dword loads, 5 ds_write_b32 (4-way banks) vs
// R12's 10 ds_write_b16 (8-way). LDS tile [dy(5)][wp(33)][par(2)][c(32)]
// bf16 XOR-swizzled (identical content/mapping to R12), dbuf; reused
// post-loop as [oc(128)][68] f32 for the transposed epilogue.
__global__ __launch_bounds__(1024, 4) void robin_main(
    const float* __restrict__ x, const __bf16* __restrict__ Wf,
    const float* __restrict__ bias, float* __restrict__ out) {
  __shared__ __align__(16) char smem[42240];       // 2x21120 loop / 34816 epi
  char* xb0 = smem;
  char* xb1 = smem + 21120;

  const int tid  = threadIdx.x;
  const int lane = tid & 63;
  const int wid  = tid >> 6;
  const int hb   = blockIdx.x;       // 16
  const int n    = blockIdx.y;       // 16
  const int h0   = hb * 4;

  const int ocg  = wid >> 2;         // 0..3 -> 32 oc each
  const int kp   = wid & 3;          // parity class
  const int ph   = kp >> 1, pw = kp & 1;
  const int lcol = lane & 15;        // pixel col (B) / oc row (A)
  const int lg   = lane >> 4;        // k-octet group

  // zero-fill wpair=32 pad rows (wcol 64/65), both buffers
  if (tid < 80) {
    int g  = tid & 7;
    int t2 = tid >> 3;
    int dy = t2 % 5, bi = t2 / 5;
    f32x4 z = {0.f, 0.f, 0.f, 0.f};
    *(f32x4*)((bi ? xb1 : xb0) + (dy * 33 + 32) * 128 + g * 16) = z;
  }

  // chunk-invariant B-frag base offsets (r -> +8448, hh -> +2048; deltas
  // don't touch swizzled bits 4..6)
  int boff[4];
#pragma unroll
  for (int khkw = 0; khkw < 4; ++khkw) {
    int kh = khkw >> 1, kw = khkw & 1;
    int dy0  = ph + kh;
    int wcol = 2 * lcol + pw + kw;
    int wp_  = wcol >> 1;
    boff[khkw] = ((dy0 * 33 + wp_) * 128 + (wcol & 1) * 64 + lg * 16) ^
                 ((wp_ & 7) << 4);
  }

  f32x4 acc[2][4];
#pragma unroll
  for (int m = 0; m < 2; ++m)
#pragma unroll
    for (int f = 0; f < 4; ++f) acc[m][f] = (f32x4){0.f, 0.f, 0.f, 0.f};

  const float* xbase = x + (size_t)n * C_IN * HW * HW;

  // staging partition: thread = (c-pair = 2*wid, w = lane); 5 dy rows.
  // write offset (chunk-invariant): ((k*33+wp)*128 + par*64 + c*2)^swz
  const int wp_s  = lane >> 1;
  const int par_s = lane & 1;
  const int bo_s  = ((wp_s * 128) + par_s * 64 + wid * 4) ^ ((wp_s & 7) << 4);
  float xlo[5], xhi[5];
  v8bf  a_reg[4][2];

#define A_LOAD(QQ)                                                             \
  {                                                                            \
    _Pragma("unroll") for (int khkw = 0; khkw < 4; ++khkw) {                   \
      const __bf16* wp =                                                       \
          Wf + (((size_t)(kp * 4 + khkw) * 32 + (QQ) * 4 + lg) * 128 +        \
                ocg * 32 + lcol) * 8;                                          \
      a_reg[khkw][0] = *(const v8bf*)wp;                                       \
      a_reg[khkw][1] = *(const v8bf*)(wp + 128);                               \
    }                                                                          \
  }

  // 10 coalesced dword loads: c-planes (2*wid, 2*wid+1), rows h0..h0+4
#define LOADQ(QQ)                                                              \
  {                                                                            \
    const float* bp =                                                          \
        xbase + ((size_t)((QQ) * 32 + 2 * wid)) * 4096 + h0 * 64 + lane;       \
    _Pragma("unroll") for (int k = 0; k < 4; ++k) {                            \
      xlo[k] = bp[k * 64];                                                     \
      xhi[k] = bp[4096 + k * 64];                                              \
    }                                                                          \
    if (h0 + 4 < HW) {                                                         \
      xlo[4] = bp[4 * 64];                                                     \
      xhi[4] = bp[4096 + 4 * 64];                                              \
    } else {                                                                   \
      xlo[4] = 0.f;                                                            \
      xhi[4] = 0.f;                                                            \
    }                                                                          \
  }

  // 5 ds_write_b32 per thread, 16-bank spread (4-way), offsets invariant
#define WRITEQ(QQ)                                                             \
  {                                                                            \
    char* xd = ((QQ) & 1) ? xb1 : xb0;                                         \
    _Pragma("unroll") for (int k = 0; k < 5; ++k) {                            \
      unsigned short a_ = __builtin_bit_cast(unsigned short, (__bf16)xlo[k]);  \
      unsigned short b_ = __builtin_bit_cast(unsigned short, (__bf16)xhi[k]);  \
      *(u32*)(xd + bo_s + k * 4224) = (u32)a_ | ((u32)b_ << 16);               \
    }                                                                          \
  }

#define COMPUTE(QQ)                                                            \
  {                                                                            \
    const char* xsb = ((QQ) & 1) ? xb1 : xb0;                                  \
    _Pragma("unroll") for (int khkw = 0; khkw < 4; ++khkw) {                   \
      v8bf b[4];                                                               \
      _Pragma("unroll") for (int r = 0; r < 2; ++r)                            \
        _Pragma("unroll") for (int hh = 0; hh < 2; ++hh)                       \
          b[r * 2 + hh] =                                                      \
              *(const v8bf*)(xsb + boff[khkw] + r * 8448 + hh * 2048);         \
      _Pragma("unroll") for (int m = 0; m < 2; ++m)                            \
        _Pragma("unroll") for (int f = 0; f < 4; ++f)                          \
          acc[m][f] = __builtin_amdgcn_mfma_f32_16x16x32_bf16(                 \
              a_reg[khkw][m], b[f], acc[m][f], 0, 0, 0);                       \
    }                                                                          \
  }

  // prologue: fill buffer 0 with chunk 0
  LOADQ(0);
  WRITEQ(0);
  __syncthreads();

  for (int q = 0; q < 8; ++q) {
    A_LOAD(q);                // issued FIRST (vmcnt FIFO: keep x in flight)
    if (q < 7) LOADQ(q + 1);
    COMPUTE(q);
    if (q < 7) {
      WRITEQ(q + 1);     // other buffer, free since compute(q-1)
      __syncthreads();   // writes visible before compute(q+1)
    }
  }

  // ---- epilogue: LDS transpose -> stride-1 coalesced scalar stores ----
  // acc D layout: col=lane&15 (pixel), row=(lane>>4)*4+reg (oc).
  float bv[2][4];
#pragma unroll
  for (int m = 0; m < 2; ++m)
#pragma unroll
    for (int reg = 0; reg < 4; ++reg)
      bv[m][reg] = bias[(ocg * 32 + m * 16 + lg * 4 + reg) * 4 + kp];

  float* eb = (float*)smem;          // [oc(128)][68] f32 = 34816 B
#pragma unroll
  for (int p = 0; p < 4; ++p) {
    const int h = h0 + p;
    __syncthreads();                 // prev pass reads / loop reads done
    if ((ph == (p & 1)) && h < OHW) {
      const int rsel = p >> 1;
#pragma unroll
      for (int m = 0; m < 2; ++m)
#pragma unroll
        for (int hh = 0; hh < 2; ++hh) {
          f32x4 v = acc[m][rsel * 2 + hh];
          int w = 2 * (hh * 16 + lcol) + pw;       // <= 63
#pragma unroll
          for (int reg = 0; reg < 4; ++reg)
            eb[(ocg * 32 + m * 16 + lg * 4 + reg) * 68 + w] =
                v[reg] + bv[m][reg];
        }
    }
    __syncthreads();                 // tile complete
    if (h < OHW) {
      const int lc2 = tid & 15;
#pragma unroll
      for (int s = 0; s < 2; ++s) {
        int oc = (tid >> 4) + (s << 6);
        float* orow = out + ((size_t)(n * NOC + oc) * OHW + h) * OHW;
        const float* erow = eb + oc * 68;
#pragma unroll
        for (int b = 0; b < 4; ++b) {
          int w = lc2 + 16 * b;
          if (w < OHW) orow[w] = erow[w];
        }
      }
    }
  }
#undef A_LOAD
#undef LOADQ
#undef WRITEQ
#undef COMPUTE
}

extern "C" void kernel_launch(void* const* d_in, const int* in_sizes, int n_in,
                              void* d_out, int out_size, void* d_ws, size_t ws_size,
                              hipStream_t stream) {
  const float* x      = (const float*)d_in[0];
  const float* weight = (const float*)d_in[1];
  const float* bias   = (const float*)d_in[2];
  float* out          = (float*)d_out;
  __bf16* Wf          = (__bf16*)d_ws;   // 1 MiB fragment-ordered weights

  wprep<<<512, 256, 0, stream>>>(weight, Wf);
  robin_main<<<dim3(16, 16), 1024, 0, stream>>>(x, Wf, bias, out);
}

// Round 15
// 42.066 us; speedup vs baseline: 1.1304x; 1.0203x over previous
//
#include <hip/hip_runtime.h>

typedef __bf16 v8bf __attribute__((ext_vector_type(8)));
typedef float f32x4 __attribute__((ext_vector_type(4)));
typedef unsigned int u32;

#define C_IN 256
#define HW   64
#define OHW  63
#define NOC  128
#define BUFSZ 21120

// Wf: [kp(4)][khkw(4)][cblk(32)][oc(128)][j(8)] bf16, 1 MiB. Coalesced.
__global__ void wprep(const float* __restrict__ w, __bf16* __restrict__ Wf) {
  int f = blockIdx.x;                 // 512 filters
  int c = threadIdx.x;                // 256 channels
  f32x4 v = *(const f32x4*)(w + (size_t)f * 1024 + c * 4);  // 4 khkw taps
  int oc = f >> 2, kp = f & 3;
#pragma unroll
  for (int khkw = 0; khkw < 4; ++khkw)
    Wf[(((size_t)(kp * 4 + khkw) * 32 + (c >> 3)) * 128 + oc) * 8 + (c & 7)] =
        (__bf16)v[khkw];
}

// R14 structure + 4-buffer LDS pipeline (barrier every 2 chunks).
// Block: n x 4 out rows x 128 oc, 1024 thr (16 waves, 4/SIMD).
// Slot q: A(q); WRITEQ(q+2 -> buf (q+2)&3) from bank[q&1] (waits only x
// issued at slot q-1; A(q) is newer so it stays); LOADQ(q+3) -> bank[(q+1)&1];
// COMPUTE(q, buf q&3) (waits A(q); x stays in flight); barrier after odd q.
// Hazard table verified: every write/read pair on each buffer is separated
// by >=1 barrier; xr banks strictly in-order.
__global__ __launch_bounds__(1024, 4) void robin_main(
    const float* __restrict__ x, const __bf16* __restrict__ Wf,
    const float* __restrict__ bias, float* __restrict__ out) {
  __shared__ __align__(16) char smem[4 * BUFSZ];   // 84480 loop / 34816 epi

  const int tid  = threadIdx.x;
  const int lane = tid & 63;
  const int wid  = tid >> 6;
  const int hb   = blockIdx.x;       // 16
  const int n    = blockIdx.y;       // 16
  const int h0   = hb * 4;

  const int ocg  = wid >> 2;         // 0..3 -> 32 oc each
  const int kp   = wid & 3;          // parity class
  const int ph   = kp >> 1, pw = kp & 1;
  const int lcol = lane & 15;        // pixel col (B) / oc row (A)
  const int lg   = lane >> 4;        // k-octet group

  // zero-fill wpair=32 pad rows (wcol 64/65), all 4 buffers
  if (tid < 160) {
    int g  = tid & 7;
    int t2 = tid >> 3;
    int dy = t2 % 5, bi = t2 / 5;    // bi 0..3
    f32x4 z = {0.f, 0.f, 0.f, 0.f};
    *(f32x4*)(smem + bi * BUFSZ + (dy * 33 + 32) * 128 + g * 16) = z;
  }

  // chunk-invariant B-frag base offsets (r -> +8448, hh -> +2048)
  int boff[4];
#pragma unroll
  for (int khkw = 0; khkw < 4; ++khkw) {
    int kh = khkw >> 1, kw = khkw & 1;
    int dy0  = ph + kh;
    int wcol = 2 * lcol + pw + kw;
    int wp_  = wcol >> 1;
    boff[khkw] = ((dy0 * 33 + wp_) * 128 + (wcol & 1) * 64 + lg * 16) ^
                 ((wp_ & 7) << 4);
  }

  f32x4 acc[2][4];
#pragma unroll
  for (int m = 0; m < 2; ++m)
#pragma unroll
    for (int f = 0; f < 4; ++f) acc[m][f] = (f32x4){0.f, 0.f, 0.f, 0.f};

  const float* xbase = x + (size_t)n * C_IN * HW * HW;

  // staging partition (R14): thread = c-pair (2*wid, 2*wid+1) at w=lane.
  const int wp_s  = lane >> 1;
  const int par_s = lane & 1;
  const int bo_s  = ((wp_s * 128) + par_s * 64 + wid * 4) ^ ((wp_s & 7) << 4);
  float xloA[5], xhiA[5], xloB[5], xhiB[5];
  v8bf  a_reg[4][2];

#define A_LOAD(QQ)                                                             \
  {                                                                            \
    _Pragma("unroll") for (int khkw = 0; khkw < 4; ++khkw) {                   \
      const __bf16* wp =                                                       \
          Wf + (((size_t)(kp * 4 + khkw) * 32 + (QQ) * 4 + lg) * 128 +        \
                ocg * 32 + lcol) * 8;                                          \
      a_reg[khkw][0] = *(const v8bf*)wp;                                       \
      a_reg[khkw][1] = *(const v8bf*)(wp + 128);                               \
    }                                                                          \
  }

  // 10 coalesced dword loads: c-planes (2*wid, 2*wid+1), rows h0..h0+4
#define LOADQ(QQ, XLO, XHI)                                                    \
  {                                                                            \
    const float* bp =                                                          \
        xbase + ((size_t)((QQ) * 32 + 2 * wid)) * 4096 + h0 * 64 + lane;       \
    _Pragma("unroll") for (int k = 0; k < 4; ++k) {                            \
      XLO[k] = bp[k * 64];                                                     \
      XHI[k] = bp[4096 + k * 64];                                              \
    }                                                                          \
    if (h0 + 4 < HW) {                                                         \
      XLO[4] = bp[4 * 64];                                                     \
      XHI[4] = bp[4096 + 4 * 64];                                              \
    } else {                                                                   \
      XLO[4] = 0.f;                                                            \
      XHI[4] = 0.f;                                                            \
    }                                                                          \
  }

  // 5 ds_write_b32 per thread into buf (QQ)&3
#define WRITEQ(QQ, XLO, XHI)                                                   \
  {                                                                            \
    char* xd = smem + ((QQ) & 3) * BUFSZ;                                      \
    _Pragma("unroll") for (int k = 0; k < 5; ++k) {                            \
      unsigned short a_ = __builtin_bit_cast(unsigned short, (__bf16)XLO[k]);  \
      unsigned short b_ = __builtin_bit_cast(unsigned short, (__bf16)XHI[k]);  \
      *(u32*)(xd + bo_s + k * 4224) = (u32)a_ | ((u32)b_ << 16);               \
    }                                                                          \
  }

#define COMPUTE(QQ)                                                            \
  {                                                                            \
    const char* xsb = smem + ((QQ) & 3) * BUFSZ;                               \
    _Pragma("unroll") for (int khkw = 0; khkw < 4; ++khkw) {                   \
      v8bf b[4];                                                               \
      _Pragma("unroll") for (int r = 0; r < 2; ++r)                            \
        _Pragma("unroll") for (int hh = 0; hh < 2; ++hh)                       \
          b[r * 2 + hh] =                                                      \
              *(const v8bf*)(xsb + boff[khkw] + r * 8448 + hh * 2048);         \
      _Pragma("unroll") for (int m = 0; m < 2; ++m)                            \
        _Pragma("unroll") for (int f = 0; f < 4; ++f)                          \
          acc[m][f] = __builtin_amdgcn_mfma_f32_16x16x32_bf16(                 \
              a_reg[khkw][m], b[f], acc[m][f], 0, 0, 0);                       \
    }                                                                          \
  }

  // prologue: chunks 0,1 -> bufs 0,1; chunk 2 -> bank A (written at slot 0)
  LOADQ(0, xloA, xhiA);
  WRITEQ(0, xloA, xhiA);
  LOADQ(1, xloB, xhiB);
  WRITEQ(1, xloB, xhiB);
  LOADQ(2, xloA, xhiA);
  __syncthreads();

  // slots 0..5 as 3 rolled pairs; even slot: W<-A, L->B; odd: W<-B, L->A
  for (int p = 0; p < 3; ++p) {
    const int q0 = 2 * p;
    // slot q0 (even)
    A_LOAD(q0);
    WRITEQ(q0 + 2, xloA, xhiA);          // waits x(q0+2) [slot q0-1]; A stays
    LOADQ(q0 + 3, xloB, xhiB);
    COMPUTE(q0);                          // waits A(q0); x(q0+3) stays
    // slot q0+1 (odd)
    A_LOAD(q0 + 1);
    WRITEQ(q0 + 3, xloB, xhiB);
    if (p < 2) LOADQ(q0 + 4, xloA, xhiA);
    COMPUTE(q0 + 1);
    __syncthreads();                      // barrier every 2 chunks
  }
  // tail: slots 6,7 (all buffers already written; last barrier after slot 5)
  A_LOAD(6);
  COMPUTE(6);
  A_LOAD(7);
  COMPUTE(7);

  // ---- epilogue: LDS transpose -> stride-1 coalesced scalar stores ----
  float bv[2][4];
#pragma unroll
  for (int m = 0; m < 2; ++m)
#pragma unroll
    for (int reg = 0; reg < 4; ++reg)
      bv[m][reg] = bias[(ocg * 32 + m * 16 + lg * 4 + reg) * 4 + kp];

  float* eb = (float*)smem;          // [oc(128)][68] f32 = 34816 B
#pragma unroll
  for (int p = 0; p < 4; ++p) {
    const int h = h0 + p;
    __syncthreads();                 // loop reads / prev pass reads done
    if ((ph == (p & 1)) && h < OHW) {
      const int rsel = p >> 1;
#pragma unroll
      for (int m = 0; m < 2; ++m)
#pragma unroll
        for (int hh = 0; hh < 2; ++hh) {
          f32x4 v = acc[m][rsel * 2 + hh];
          int w = 2 * (hh * 16 + lcol) + pw;       // <= 63
#pragma unroll
          for (int reg = 0; reg < 4; ++reg)
            eb[(ocg * 32 + m * 16 + lg * 4 + reg) * 68 + w] =
                v[reg] + bv[m][reg];
        }
    }
    __syncthreads();                 // tile complete
    if (h < OHW) {
      const int lc2 = tid & 15;
#pragma unroll
      for (int s = 0; s < 2; ++s) {
        int oc = (tid >> 4) + (s << 6);
        float* orow = out + ((size_t)(n * NOC + oc) * OHW + h) * OHW;
        const float* erow = eb + oc * 68;
#pragma unroll
        for (int b = 0; b < 4; ++b) {
          int w = lc2 + 16 * b;
          if (w < OHW) orow[w] = erow[w];
        }
      }
    }
  }
#undef A_LOAD
#undef LOADQ
#undef WRITEQ
#undef COMPUTE
}

extern "C" void kernel_launch(void* const* d_in, const int* in_sizes, int n_in,
                              void* d_out, int out_size, void* d_ws, size_t ws_size,
                              hipStream_t stream) {
  const float* x      = (const float*)d_in[0];
  const float* weight = (const float*)d_in[1];
  const float* bias   = (const float*)d_in[2];
  float* out          = (float*)d_out;
  __bf16* Wf          = (__bf16*)d_ws;   // 1 MiB fragment-ordered weights

  wprep<<<512, 256, 0, stream>>>(weight, Wf);
  robin_main<<<dim3(16, 16), 1024, 0, stream>>>(x, Wf, bias, out);
}

// Round 16
// 41.518 us; speedup vs baseline: 1.1453x; 1.0132x over previous
//
#include <hip/hip_runtime.h>

typedef __bf16 v8bf __attribute__((ext_vector_type(8)));
typedef float f32x4 __attribute__((ext_vector_type(4)));
typedef unsigned int u32;

#define C_IN 256
#define HW   64
#define OHW  63
#define NOC  128
#define BUFSZ 21120

// Wf: [kp(4)][khkw(4)][cblk(32)][oc(128)][j(8)] bf16, 1 MiB. Coalesced.
__global__ void wprep(const float* __restrict__ w, __bf16* __restrict__ Wf) {
  int f = blockIdx.x;                 // 512 filters
  int c = threadIdx.x;                // 256 channels
  f32x4 v = *(const f32x4*)(w + (size_t)f * 1024 + c * 4);  // 4 khkw taps
  int oc = f >> 2, kp = f & 3;
#pragma unroll
  for (int khkw = 0; khkw < 4; ++khkw)
    Wf[(((size_t)(kp * 4 + khkw) * 32 + (c >> 3)) * 128 + oc) * 8 + (c & 7)] =
        (__bf16)v[khkw];
}

// R15 + (a) T5 setprio around MFMA clusters, (b) 2-pass epilogue (row-pair
// per pass, all waves active, 4 barriers instead of 8).
// Block: n x 4 out rows x 128 oc, 1024 thr (16 waves, 4/SIMD).
// 4-buffer LDS pipeline, barrier every 2 chunks (R15 hazard table).
__global__ __launch_bounds__(1024, 4) void robin_main(
    const float* __restrict__ x, const __bf16* __restrict__ Wf,
    const float* __restrict__ bias, float* __restrict__ out) {
  __shared__ __align__(16) char smem[4 * BUFSZ];   // 84480 loop / 69632 epi

  const int tid  = threadIdx.x;
  const int lane = tid & 63;
  const int wid  = tid >> 6;
  const int hb   = blockIdx.x;       // 16
  const int n    = blockIdx.y;       // 16
  const int h0   = hb * 4;

  const int ocg  = wid >> 2;         // 0..3 -> 32 oc each
  const int kp   = wid & 3;          // parity class
  const int ph   = kp >> 1, pw = kp & 1;
  const int lcol = lane & 15;        // pixel col (B) / oc row (A)
  const int lg   = lane >> 4;        // k-octet group

  // zero-fill wpair=32 pad rows (wcol 64/65), all 4 buffers
  if (tid < 160) {
    int g  = tid & 7;
    int t2 = tid >> 3;
    int dy = t2 % 5, bi = t2 / 5;    // bi 0..3
    f32x4 z = {0.f, 0.f, 0.f, 0.f};
    *(f32x4*)(smem + bi * BUFSZ + (dy * 33 + 32) * 128 + g * 16) = z;
  }

  // chunk-invariant B-frag base offsets (r -> +8448, hh -> +2048)
  int boff[4];
#pragma unroll
  for (int khkw = 0; khkw < 4; ++khkw) {
    int kh = khkw >> 1, kw = khkw & 1;
    int dy0  = ph + kh;
    int wcol = 2 * lcol + pw + kw;
    int wp_  = wcol >> 1;
    boff[khkw] = ((dy0 * 33 + wp_) * 128 + (wcol & 1) * 64 + lg * 16) ^
                 ((wp_ & 7) << 4);
  }

  f32x4 acc[2][4];
#pragma unroll
  for (int m = 0; m < 2; ++m)
#pragma unroll
    for (int f = 0; f < 4; ++f) acc[m][f] = (f32x4){0.f, 0.f, 0.f, 0.f};

  const float* xbase = x + (size_t)n * C_IN * HW * HW;

  // staging partition (R14): thread = c-pair (2*wid, 2*wid+1) at w=lane.
  const int wp_s  = lane >> 1;
  const int par_s = lane & 1;
  const int bo_s  = ((wp_s * 128) + par_s * 64 + wid * 4) ^ ((wp_s & 7) << 4);
  float xloA[5], xhiA[5], xloB[5], xhiB[5];
  v8bf  a_reg[4][2];

#define A_LOAD(QQ)                                                             \
  {                                                                            \
    _Pragma("unroll") for (int khkw = 0; khkw < 4; ++khkw) {                   \
      const __bf16* wp =                                                       \
          Wf + (((size_t)(kp * 4 + khkw) * 32 + (QQ) * 4 + lg) * 128 +        \
                ocg * 32 + lcol) * 8;                                          \
      a_reg[khkw][0] = *(const v8bf*)wp;                                       \
      a_reg[khkw][1] = *(const v8bf*)(wp + 128);                               \
    }                                                                          \
  }

  // 10 coalesced dword loads: c-planes (2*wid, 2*wid+1), rows h0..h0+4
#define LOADQ(QQ, XLO, XHI)                                                    \
  {                                                                            \
    const float* bp =                                                          \
        xbase + ((size_t)((QQ) * 32 + 2 * wid)) * 4096 + h0 * 64 + lane;       \
    _Pragma("unroll") for (int k = 0; k < 4; ++k) {                            \
      XLO[k] = bp[k * 64];                                                     \
      XHI[k] = bp[4096 + k * 64];                                              \
    }                                                                          \
    if (h0 + 4 < HW) {                                                         \
      XLO[4] = bp[4 * 64];                                                     \
      XHI[4] = bp[4096 + 4 * 64];                                              \
    } else {                                                                   \
      XLO[4] = 0.f;                                                            \
      XHI[4] = 0.f;                                                            \
    }                                                                          \
  }

  // 5 ds_write_b32 per thread into buf (QQ)&3
#define WRITEQ(QQ, XLO, XHI)                                                   \
  {                                                                            \
    char* xd = smem + ((QQ) & 3) * BUFSZ;                                      \
    _Pragma("unroll") for (int k = 0; k < 5; ++k) {                            \
      unsigned short a_ = __builtin_bit_cast(unsigned short, (__bf16)XLO[k]);  \
      unsigned short b_ = __builtin_bit_cast(unsigned short, (__bf16)XHI[k]);  \
      *(u32*)(xd + bo_s + k * 4224) = (u32)a_ | ((u32)b_ << 16);               \
    }                                                                          \
  }

#define COMPUTE(QQ)                                                            \
  {                                                                            \
    const char* xsb = smem + ((QQ) & 3) * BUFSZ;                               \
    _Pragma("unroll") for (int khkw = 0; khkw < 4; ++khkw) {                   \
      v8bf b[4];                                                               \
      _Pragma("unroll") for (int r = 0; r < 2; ++r)                            \
        _Pragma("unroll") for (int hh = 0; hh < 2; ++hh)                       \
          b[r * 2 + hh] =                                                      \
              *(const v8bf*)(xsb + boff[khkw] + r * 8448 + hh * 2048);         \
      __builtin_amdgcn_s_setprio(1);                                           \
      _Pragma("unroll") for (int m = 0; m < 2; ++m)                            \
        _Pragma("unroll") for (int f = 0; f < 4; ++f)                          \
          acc[m][f] = __builtin_amdgcn_mfma_f32_16x16x32_bf16(                 \
              a_reg[khkw][m], b[f], acc[m][f], 0, 0, 0);                       \
      __builtin_amdgcn_s_setprio(0);                                           \
    }                                                                          \
  }

  // prologue: chunks 0,1 -> bufs 0,1; chunk 2 -> bank A (written at slot 0)
  LOADQ(0, xloA, xhiA);
  WRITEQ(0, xloA, xhiA);
  LOADQ(1, xloB, xhiB);
  WRITEQ(1, xloB, xhiB);
  LOADQ(2, xloA, xhiA);
  __syncthreads();

  // slots 0..5 as 3 rolled pairs; even slot: W<-A, L->B; odd: W<-B, L->A
  for (int p = 0; p < 3; ++p) {
    const int q0 = 2 * p;
    // slot q0 (even)
    A_LOAD(q0);
    WRITEQ(q0 + 2, xloA, xhiA);          // waits x(q0+2) [slot q0-1]; A stays
    LOADQ(q0 + 3, xloB, xhiB);
    COMPUTE(q0);                          // waits A(q0); x(q0+3) stays
    // slot q0+1 (odd)
    A_LOAD(q0 + 1);
    WRITEQ(q0 + 3, xloB, xhiB);
    if (p < 2) LOADQ(q0 + 4, xloA, xhiA);
    COMPUTE(q0 + 1);
    __syncthreads();                      // barrier every 2 chunks
  }
  // tail: slots 6,7 (all buffers already written; last barrier after slot 5)
  A_LOAD(6);
  COMPUTE(6);
  A_LOAD(7);
  COMPUTE(7);

  // ---- epilogue: 2 passes, row-pair per pass, all waves active ----
  // acc D layout: col=lane&15 (pixel), row=(lane>>4)*4+reg (oc).
  // eb layout: [rr=ph(2)][oc(128)][68] f32 = 69632 B.
  float bv[2][4];
#pragma unroll
  for (int m = 0; m < 2; ++m)
#pragma unroll
    for (int reg = 0; reg < 4; ++reg)
      bv[m][reg] = bias[(ocg * 32 + m * 16 + lg * 4 + reg) * 4 + kp];

  float* eb = (float*)smem;
#pragma unroll
  for (int p = 0; p < 2; ++p) {
    __syncthreads();                 // loop reads / prev pass reads done
    // every wave writes its r=p fragments into row rr=ph
    {
#pragma unroll
      for (int m = 0; m < 2; ++m)
#pragma unroll
        for (int hh = 0; hh < 2; ++hh) {
          f32x4 v = acc[m][p * 2 + hh];
          int w = 2 * (hh * 16 + lcol) + pw;       // <= 63
#pragma unroll
          for (int reg = 0; reg < 4; ++reg)
            eb[((ph << 7) + ocg * 32 + m * 16 + lg * 4 + reg) * 68 + w] =
                v[reg] + bv[m][reg];
        }
    }
    __syncthreads();                 // tile complete
#pragma unroll
    for (int s = 0; s < 4; ++s) {
      int rowid = (tid >> 4) + (s << 6);           // 0..255 = rr*128 + oc
      int rr = rowid >> 7, oc = rowid & 127;
      int h = h0 + 2 * p + rr;
      if (h < OHW) {
        const float* erow = eb + rowid * 68;
        float* orow = out + ((size_t)(n * NOC + oc) * OHW + h) * OHW;
        const int lc2 = tid & 15;
#pragma unroll
        for (int b = 0; b < 4; ++b) {
          int w = lc2 + 16 * b;
          if (w < OHW) orow[w] = erow[w];
        }
      }
    }
  }
#undef A_LOAD
#undef LOADQ
#undef WRITEQ
#undef COMPUTE
}

extern "C" void kernel_launch(void* const* d_in, const int* in_sizes, int n_in,
                              void* d_out, int out_size, void* d_ws, size_t ws_size,
                              hipStream_t stream) {
  const float* x      = (const float*)d_in[0];
  const float* weight = (const float*)d_in[1];
  const float* bias   = (const float*)d_in[2];
  float* out          = (float*)d_out;
  __bf16* Wf          = (__bf16*)d_ws;   // 1 MiB fragment-ordered weights

  wprep<<<512, 256, 0, stream>>>(weight, Wf);
  robin_main<<<dim3(16, 16), 1024, 0, stream>>>(x, Wf, bias, out);
}

// Round 17
// 38.487 us; speedup vs baseline: 1.2355x; 1.0788x over previous
//
#include <hip/hip_runtime.h>

typedef __bf16 v8bf __attribute__((ext_vector_type(8)));
typedef float f32x4 __attribute__((ext_vector_type(4)));
typedef unsigned int u32;

#define C_IN 256
#define HW   64
#define OHW  63
#define NOC  128
#define BUFSZ 21120

// Wf: [kp(4)][khkw(4)][cblk(32)][oc(128)][j(8)] bf16, 1 MiB. Coalesced.
__global__ void wprep(const float* __restrict__ w, __bf16* __restrict__ Wf) {
  int f = blockIdx.x;                 // 512 filters
  int c = threadIdx.x;                // 256 channels
  f32x4 v = *(const f32x4*)(w + (size_t)f * 1024 + c * 4);  // 4 khkw taps
  int oc = f >> 2, kp = f & 3;
#pragma unroll
  for (int khkw = 0; khkw < 4; ++khkw)
    Wf[(((size_t)(kp * 4 + khkw) * 32 + (c >> 3)) * 128 + oc) * 8 + (c & 7)] =
        (__bf16)v[khkw];
}

// R16 + T1 XCD-aware block swizzle. 1-D grid 256; XCD k (= bid&7) owns the
// full 16-strip column for n in {2k, 2k+1}, so the dy=4 row shared by
// strips (hb, hb+1) is an L2 hit instead of an HBM refetch (~15 MB saved).
// Block: n x 4 out rows x 128 oc, 1024 thr (16 waves, 4/SIMD).
// 4-buffer LDS pipeline, barrier every 2 chunks; setprio around MFMA;
// 2-pass LDS-transposed epilogue.
__global__ __launch_bounds__(1024, 4) void robin_main(
    const float* __restrict__ x, const __bf16* __restrict__ Wf,
    const float* __restrict__ bias, float* __restrict__ out) {
  __shared__ __align__(16) char smem[4 * BUFSZ];   // 84480 loop / 69632 epi

  const int tid  = threadIdx.x;
  const int lane = tid & 63;
  const int wid  = tid >> 6;
  const int bid  = blockIdx.x;       // 256, swizzled decode below
  const int hb   = (bid >> 3) & 15;  // strip: same-XCD blocks share n-column
  const int n    = ((bid & 7) << 1) | (bid >> 7);
  const int h0   = hb * 4;

  const int ocg  = wid >> 2;         // 0..3 -> 32 oc each
  const int kp   = wid & 3;          // parity class
  const int ph   = kp >> 1, pw = kp & 1;
  const int lcol = lane & 15;        // pixel col (B) / oc row (A)
  const int lg   = lane >> 4;        // k-octet group

  // zero-fill wpair=32 pad rows (wcol 64/65), all 4 buffers
  if (tid < 160) {
    int g  = tid & 7;
    int t2 = tid >> 3;
    int dy = t2 % 5, bi = t2 / 5;    // bi 0..3
    f32x4 z = {0.f, 0.f, 0.f, 0.f};
    *(f32x4*)(smem + bi * BUFSZ + (dy * 33 + 32) * 128 + g * 16) = z;
  }

  // chunk-invariant B-frag base offsets (r -> +8448, hh -> +2048)
  int boff[4];
#pragma unroll
  for (int khkw = 0; khkw < 4; ++khkw) {
    int kh = khkw >> 1, kw = khkw & 1;
    int dy0  = ph + kh;
    int wcol = 2 * lcol + pw + kw;
    int wp_  = wcol >> 1;
    boff[khkw] = ((dy0 * 33 + wp_) * 128 + (wcol & 1) * 64 + lg * 16) ^
                 ((wp_ & 7) << 4);
  }

  f32x4 acc[2][4];
#pragma unroll
  for (int m = 0; m < 2; ++m)
#pragma unroll
    for (int f = 0; f < 4; ++f) acc[m][f] = (f32x4){0.f, 0.f, 0.f, 0.f};

  const float* xbase = x + (size_t)n * C_IN * HW * HW;

  // staging partition (R14): thread = c-pair (2*wid, 2*wid+1) at w=lane.
  const int wp_s  = lane >> 1;
  const int par_s = lane & 1;
  const int bo_s  = ((wp_s * 128) + par_s * 64 + wid * 4) ^ ((wp_s & 7) << 4);
  float xloA[5], xhiA[5], xloB[5], xhiB[5];
  v8bf  a_reg[4][2];

#define A_LOAD(QQ)                                                             \
  {                                                                            \
    _Pragma("unroll") for (int khkw = 0; khkw < 4; ++khkw) {                   \
      const __bf16* wp =                                                       \
          Wf + (((size_t)(kp * 4 + khkw) * 32 + (QQ) * 4 + lg) * 128 +        \
                ocg * 32 + lcol) * 8;                                          \
      a_reg[khkw][0] = *(const v8bf*)wp;                                       \
      a_reg[khkw][1] = *(const v8bf*)(wp + 128);                               \
    }                                                                          \
  }

  // 10 coalesced dword loads: c-planes (2*wid, 2*wid+1), rows h0..h0+4
#define LOADQ(QQ, XLO, XHI)                                                    \
  {                                                                            \
    const float* bp =                                                          \
        xbase + ((size_t)((QQ) * 32 + 2 * wid)) * 4096 + h0 * 64 + lane;       \
    _Pragma("unroll") for (int k = 0; k < 4; ++k) {                            \
      XLO[k] = bp[k * 64];                                                     \
      XHI[k] = bp[4096 + k * 64];                                              \
    }                                                                          \
    if (h0 + 4 < HW) {                                                         \
      XLO[4] = bp[4 * 64];                                                     \
      XHI[4] = bp[4096 + 4 * 64];                                              \
    } else {                                                                   \
      XLO[4] = 0.f;                                                            \
      XHI[4] = 0.f;                                                            \
    }                                                                          \
  }

  // 5 ds_write_b32 per thread into buf (QQ)&3
#define WRITEQ(QQ, XLO, XHI)                                                   \
  {                                                                            \
    char* xd = smem + ((QQ) & 3) * BUFSZ;                                      \
    _Pragma("unroll") for (int k = 0; k < 5; ++k) {                            \
      unsigned short a_ = __builtin_bit_cast(unsigned short, (__bf16)XLO[k]);  \
      unsigned short b_ = __builtin_bit_cast(unsigned short, (__bf16)XHI[k]);  \
      *(u32*)(xd + bo_s + k * 4224) = (u32)a_ | ((u32)b_ << 16);               \
    }                                                                          \
  }

#define COMPUTE(QQ)                                                            \
  {                                                                            \
    const char* xsb = smem + ((QQ) & 3) * BUFSZ;                               \
    _Pragma("unroll") for (int khkw = 0; khkw < 4; ++khkw) {                   \
      v8bf b[4];                                                               \
      _Pragma("unroll") for (int r = 0; r < 2; ++r)                            \
        _Pragma("unroll") for (int hh = 0; hh < 2; ++hh)                       \
          b[r * 2 + hh] =                                                      \
              *(const v8bf*)(xsb + boff[khkw] + r * 8448 + hh * 2048);         \
      __builtin_amdgcn_s_setprio(1);                                           \
      _Pragma("unroll") for (int m = 0; m < 2; ++m)                            \
        _Pragma("unroll") for (int f = 0; f < 4; ++f)                          \
          acc[m][f] = __builtin_amdgcn_mfma_f32_16x16x32_bf16(                 \
              a_reg[khkw][m], b[f], acc[m][f], 0, 0, 0);                       \
      __builtin_amdgcn_s_setprio(0);                                           \
    }                                                                          \
  }

  // prologue: chunks 0,1 -> bufs 0,1; chunk 2 -> bank A (written at slot 0)
  LOADQ(0, xloA, xhiA);
  WRITEQ(0, xloA, xhiA);
  LOADQ(1, xloB, xhiB);
  WRITEQ(1, xloB, xhiB);
  LOADQ(2, xloA, xhiA);
  __syncthreads();

  // slots 0..5 as 3 rolled pairs; even slot: W<-A, L->B; odd: W<-B, L->A
  for (int p = 0; p < 3; ++p) {
    const int q0 = 2 * p;
    // slot q0 (even)
    A_LOAD(q0);
    WRITEQ(q0 + 2, xloA, xhiA);          // waits x(q0+2) [slot q0-1]; A stays
    LOADQ(q0 + 3, xloB, xhiB);
    COMPUTE(q0);                          // waits A(q0); x(q0+3) stays
    // slot q0+1 (odd)
    A_LOAD(q0 + 1);
    WRITEQ(q0 + 3, xloB, xhiB);
    if (p < 2) LOADQ(q0 + 4, xloA, xhiA);
    COMPUTE(q0 + 1);
    __syncthreads();                      // barrier every 2 chunks
  }
  // tail: slots 6,7 (all buffers already written; last barrier after slot 5)
  A_LOAD(6);
  COMPUTE(6);
  A_LOAD(7);
  COMPUTE(7);

  // ---- epilogue: 2 passes, row-pair per pass, all waves active ----
  // acc D layout: col=lane&15 (pixel), row=(lane>>4)*4+reg (oc).
  // eb layout: [rr=ph(2)][oc(128)][68] f32 = 69632 B.
  float bv[2][4];
#pragma unroll
  for (int m = 0; m < 2; ++m)
#pragma unroll
    for (int reg = 0; reg < 4; ++reg)
      bv[m][reg] = bias[(ocg * 32 + m * 16 + lg * 4 + reg) * 4 + kp];

  float* eb = (float*)smem;
#pragma unroll
  for (int p = 0; p < 2; ++p) {
    __syncthreads();                 // loop reads / prev pass reads done
    // every wave writes its r=p fragments into row rr=ph
    {
#pragma unroll
      for (int m = 0; m < 2; ++m)
#pragma unroll
        for (int hh = 0; hh < 2; ++hh) {
          f32x4 v = acc[m][p * 2 + hh];
          int w = 2 * (hh * 16 + lcol) + pw;       // <= 63
#pragma unroll
          for (int reg = 0; reg < 4; ++reg)
            eb[((ph << 7) + ocg * 32 + m * 16 + lg * 4 + reg) * 68 + w] =
                v[reg] + bv[m][reg];
        }
    }
    __syncthreads();                 // tile complete
#pragma unroll
    for (int s = 0; s < 4; ++s) {
      int rowid = (tid >> 4) + (s << 6);           // 0..255 = rr*128 + oc
      int rr = rowid >> 7, oc = rowid & 127;
      int h = h0 + 2 * p + rr;
      if (h < OHW) {
        const float* erow = eb + rowid * 68;
        float* orow = out + ((size_t)(n * NOC + oc) * OHW + h) * OHW;
        const int lc2 = tid & 15;
#pragma unroll
        for (int b = 0; b < 4; ++b) {
          int w = lc2 + 16 * b;
          if (w < OHW) orow[w] = erow[w];
        }
      }
    }
  }
#undef A_LOAD
#undef LOADQ
#undef WRITEQ
#undef COMPUTE
}

extern "C" void kernel_launch(void* const* d_in, const int* in_sizes, int n_in,
                              void* d_out, int out_size, void* d_ws, size_t ws_size,
                              hipStream_t stream) {
  const float* x      = (const float*)d_in[0];
  const float* weight = (const float*)d_in[1];
  const float* bias   = (const float*)d_in[2];
  float* out          = (float*)d_out;
  __bf16* Wf          = (__bf16*)d_ws;   // 1 MiB fragment-ordered weights

  wprep<<<512, 256, 0, stream>>>(weight, Wf);
  robin_main<<<256, 1024, 0, stream>>>(x, Wf, bias, out);
}